// Round 1
// baseline (247.962 us; speedup 1.0000x reference)
//
#include <hip/hip_runtime.h>
#include <hip/hip_bf16.h>

typedef __bf16 bf16_t;
typedef bf16_t bf16x8 __attribute__((ext_vector_type(8)));
typedef float f32x4 __attribute__((ext_vector_type(4)));

#define SEQ    2048
#define NHEAD  16
#define DHEAD  64
#define DMODEL 1024
#define NT     32   // SEQ / 64
#define BH     64   // B * NHEAD

__device__ __forceinline__ f32x4 mfma16(bf16x8 a, bf16x8 b, f32x4 c) {
  return __builtin_amdgcn_mfma_f32_16x16x32_bf16(a, b, c, 0, 0, 0);
}

// ---------------------------------------------------------------------------
// Kernel 1: per-head QKV projection.  x [B,S,D] fp32 -> Q/K/V bf16 [BH][S][DK]
// Block: 256 thr, handles 256 s-rows of one (b,h). grid (8, 64).
// ---------------------------------------------------------------------------
__global__ __launch_bounds__(256) void qkv_kernel(
    const float* __restrict__ x,
    const float* __restrict__ Wq, const float* __restrict__ bq,
    const float* __restrict__ Wk, const float* __restrict__ bk,
    const float* __restrict__ Wv, const float* __restrict__ bv,
    bf16_t* __restrict__ Qw, bf16_t* __restrict__ Kw, bf16_t* __restrict__ Vw) {
  __shared__ __align__(16) char x_lds[256 * 128];  // 256 rows x 64 bf16, swizzled

  const int bh = blockIdx.y;
  const int b = bh >> 4, h = bh & 15;
  const int s0 = blockIdx.x * 256;
  const int t = threadIdx.x;
  const int w = t >> 6, lane = t & 63;
  const int lo = lane & 15, g = lane >> 4;

  // stage x-chunk (head h slice) into LDS as bf16, XOR-swizzled rows of 128B
#pragma unroll
  for (int p = 0; p < 8; ++p) {
    const int row = p * 32 + (t >> 3);
    const int c = t & 7;
    const float* xp = x + ((size_t)(b * SEQ + s0 + row)) * DMODEL + h * DHEAD + c * 8;
    const float4 f0 = *(const float4*)xp;
    const float4 f1 = *(const float4*)(xp + 4);
    bf16x8 v;
    v[0] = (bf16_t)f0.x; v[1] = (bf16_t)f0.y; v[2] = (bf16_t)f0.z; v[3] = (bf16_t)f0.w;
    v[4] = (bf16_t)f1.x; v[5] = (bf16_t)f1.y; v[6] = (bf16_t)f1.z; v[7] = (bf16_t)f1.w;
    const int off = row * 128 + ((c * 16) ^ ((row & 7) << 4));
    *(bf16x8*)(x_lds + off) = v;
  }
  __syncthreads();

  for (int wi = 0; wi < 3; ++wi) {
    const float* Wp = (wi == 0) ? Wq : (wi == 1) ? Wk : Wv;
    const float* Bp = (wi == 0) ? bq : (wi == 1) ? bk : bv;
    bf16_t* Op      = (wi == 0) ? Qw : (wi == 1) ? Kw : Vw;

    // B-fragments of W[h] (64x64), k = d, n = e.  lane: n = lo, k = ks*32+g*8+i
    bf16x8 wf[4][2];
    float bias[4];
#pragma unroll
    for (int ct = 0; ct < 4; ++ct) {
      bias[ct] = Bp[h * DHEAD + ct * 16 + lo];
#pragma unroll
      for (int ks = 0; ks < 2; ++ks) {
        bf16x8 v;
#pragma unroll
        for (int i = 0; i < 8; ++i) {
          const int d = ks * 32 + g * 8 + i;
          v[i] = (bf16_t)Wp[h * DHEAD * DHEAD + d * DHEAD + (ct * 16 + lo)];
        }
        wf[ct][ks] = v;
      }
    }

#pragma unroll
    for (int it = 0; it < 4; ++it) {
      const int r0 = it * 64 + w * 16;
      bf16x8 xa[2];
#pragma unroll
      for (int ks = 0; ks < 2; ++ks) {
        const int row = r0 + lo;
        const int off = row * 128 + ((ks * 64 + g * 16) ^ ((row & 7) << 4));
        xa[ks] = *(const bf16x8*)(x_lds + off);
      }
      f32x4 acc[4];
#pragma unroll
      for (int ct = 0; ct < 4; ++ct) {
        acc[ct] = (f32x4){0.f, 0.f, 0.f, 0.f};
#pragma unroll
        for (int ks = 0; ks < 2; ++ks) acc[ct] = mfma16(xa[ks], wf[ct][ks], acc[ct]);
      }
      // store: D row = s-local g*4+r, col e = ct*16+lo
#pragma unroll
      for (int ct = 0; ct < 4; ++ct) {
#pragma unroll
        for (int r = 0; r < 4; ++r) {
          const int srow = s0 + r0 + g * 4 + r;
          Op[((size_t)bh * SEQ + srow) * DHEAD + ct * 16 + lo] =
              (bf16_t)(acc[ct][r] + bias[ct]);
        }
      }
    }
  }
}

// ---------------------------------------------------------------------------
// Kernel 2: causal flash attention. 1024 blocks (4/CU), 4 waves, QBLK=64.
// Block does q-tiles {p, 31-p} -> uniform 33 kv-steps. Writes O fp32 -> d_out.
// ---------------------------------------------------------------------------
__global__ __launch_bounds__(256) void attn_kernel(
    const bf16_t* __restrict__ Qw, const bf16_t* __restrict__ Kw,
    const bf16_t* __restrict__ Vw, float* __restrict__ Out) {
  __shared__ __align__(16) char k_lds[64 * 128];   // K rows, swizzled
  __shared__ __align__(16) char v_lds[64 * 128];   // VT[d][kv], swizzled
  __shared__ __align__(16) char p_lds[4 * 16 * 256];  // per-wave P[q][kv] fp32, swizzled

  const int f = blockIdx.x;
  const int xcd = f & 7, sub = f >> 3;
  const int bh = xcd * 8 + (sub >> 4);   // cluster each bh's 16 blocks on one XCD
  const int pair = sub & 15;
  const int b = bh >> 4, h = bh & 15;

  const int t = threadIdx.x;
  const int w = t >> 6, lane = t & 63;
  const int lo = lane & 15, g = lane >> 4;
  char* pbase = p_lds + w * 4096;

  for (int half = 0; half < 2; ++half) {
    const int qt = (half == 0) ? pair : (NT - 1 - pair);
    const int q0 = qt * 64;
    const int qw0 = q0 + w * 16;

    // Q fragments (B-operand): lane holds q-row qw0+lo, 8 consecutive d
    bf16x8 qf[2];
    {
      const bf16_t* qp = Qw + ((size_t)bh * SEQ + qw0 + lo) * DHEAD;
      qf[0] = *(const bf16x8*)(qp + g * 8);
      qf[1] = *(const bf16x8*)(qp + 32 + g * 8);
    }

    float m_run = -1e30f, l_run = 0.f;
    f32x4 oacc[4];
#pragma unroll
    for (int dt = 0; dt < 4; ++dt) oacc[dt] = (f32x4){0.f, 0.f, 0.f, 0.f};

    for (int kt = 0; kt <= qt; ++kt) {
      const int kv0 = kt * 64;
      __syncthreads();  // previous tile's LDS reads done
      {
        // K tile -> LDS, row-major swizzled
        const bf16_t* kp = Kw + ((size_t)bh * SEQ + kv0) * DHEAD;
#pragma unroll
        for (int p = 0; p < 2; ++p) {
          const int row = p * 32 + (t >> 3);
          const int c = t & 7;
          const bf16x8 kv = *(const bf16x8*)(kp + row * DHEAD + c * 8);
          *(bf16x8*)(k_lds + row * 128 + ((c * 16) ^ ((row & 7) << 4))) = kv;
        }
        // V tile -> LDS transposed: VT[d][kv], swizzled; lane=kv => banks spread
        const bf16_t* vp = Vw + ((size_t)bh * SEQ + kv0) * DHEAD;
#pragma unroll
        for (int p = 0; p < 2; ++p) {
          const int kv = lane;
          const int d0 = w * 8 + p * 32;
          const bf16x8 vv = *(const bf16x8*)(vp + kv * DHEAD + d0);
#pragma unroll
          for (int j = 0; j < 8; ++j) {
            const int d = d0 + j;
            *(bf16_t*)(v_lds + d * 128 + ((kv * 2) ^ ((d & 7) << 4))) = vv[j];
          }
        }
      }
      __syncthreads();

      // swapped QK^T: S^T[kv][q] per 16-kv subtile ct
      f32x4 sacc[4];
#pragma unroll
      for (int ct = 0; ct < 4; ++ct) {
        sacc[ct] = (f32x4){0.f, 0.f, 0.f, 0.f};
#pragma unroll
        for (int ks = 0; ks < 2; ++ks) {
          const int row = ct * 16 + lo;
          const int off = row * 128 + ((ks * 64 + g * 16) ^ ((row & 7) << 4));
          const bf16x8 kf = *(const bf16x8*)(k_lds + off);
          sacc[ct] = mfma16(kf, qf[ks], sacc[ct]);
        }
      }

      // softmax (state at q = lo)
      float s_[4][4];
      const bool diag = (kt == qt);
      const int q = qw0 + lo;
#pragma unroll
      for (int ct = 0; ct < 4; ++ct)
#pragma unroll
        for (int r = 0; r < 4; ++r) {
          float sv = sacc[ct][r] * 0.125f;
          if (diag) {
            const int kv = kv0 + ct * 16 + g * 4 + r;
            if (kv > q) sv = -1e30f;
          }
          s_[ct][r] = sv;
        }
      float m_t = -1e30f;
#pragma unroll
      for (int ct = 0; ct < 4; ++ct)
#pragma unroll
        for (int r = 0; r < 4; ++r) m_t = fmaxf(m_t, s_[ct][r]);
      m_t = fmaxf(m_t, __shfl_xor(m_t, 16));
      m_t = fmaxf(m_t, __shfl_xor(m_t, 32));
      const float m_new = fmaxf(m_run, m_t);
      const float scale = __expf(m_run - m_new);
      float l_t = 0.f;
#pragma unroll
      for (int ct = 0; ct < 4; ++ct)
#pragma unroll
        for (int r = 0; r < 4; ++r) {
          const float pv = __expf(s_[ct][r] - m_new);
          s_[ct][r] = pv;
          l_t += pv;
        }
      l_t += __shfl_xor(l_t, 16);
      l_t += __shfl_xor(l_t, 32);
      l_run = l_run * scale + l_t;
      m_run = m_new;

      // P -> LDS: row q=lo, 4 regs are 4 consecutive kv -> b128, swizzled
#pragma unroll
      for (int ct = 0; ct < 4; ++ct) {
        f32x4 pv;
#pragma unroll
        for (int r = 0; r < 4; ++r) pv[r] = s_[ct][r];
        const int off = lo * 256 + ((ct * 64 + g * 16) ^ ((lo & 7) << 4));
        *(f32x4*)(pbase + off) = pv;
      }

      // rescale O accumulator (O rows are q-local g*4+r; factor lives at lane q)
#pragma unroll
      for (int r = 0; r < 4; ++r) {
        const float fr = __shfl(scale, g * 4 + r);
#pragma unroll
        for (int dt = 0; dt < 4; ++dt) oacc[dt][r] *= fr;
      }

      // PV: A = P (from pbase), B = VT (from v_lds)
#pragma unroll
      for (int ks = 0; ks < 2; ++ks) {
        const int base = ks * 128 + g * 32;
        const int swz = (lo & 7) << 4;
        const f32x4 pa0 = *(const f32x4*)(pbase + lo * 256 + (base ^ swz));
        const f32x4 pa1 = *(const f32x4*)(pbase + lo * 256 + ((base + 16) ^ swz));
        bf16x8 pa;
#pragma unroll
        for (int i = 0; i < 4; ++i) {
          pa[i] = (bf16_t)pa0[i];
          pa[i + 4] = (bf16_t)pa1[i];
        }
#pragma unroll
        for (int dt = 0; dt < 4; ++dt) {
          const int d = dt * 16 + lo;
          const int voff = d * 128 + ((ks * 64 + g * 16) ^ ((d & 7) << 4));
          const bf16x8 vf = *(const bf16x8*)(v_lds + voff);
          oacc[dt] = mfma16(pa, vf, oacc[dt]);
        }
      }
    }  // kv tiles

    // epilogue: O * (1/l), write fp32 to d_out [B,S,D]
    const float inv = 1.0f / l_run;
#pragma unroll
    for (int r = 0; r < 4; ++r) {
      const float fr = __shfl(inv, g * 4 + r);
      const int s = qw0 + g * 4 + r;
      float* op = Out + ((size_t)b * SEQ + s) * DMODEL + h * DHEAD;
#pragma unroll
      for (int dt = 0; dt < 4; ++dt) op[dt * 16 + lo] = oacc[dt][r] * fr;
    }
  }  // half
}

// ---------------------------------------------------------------------------
// Kernel 3: residual add + LayerNorm, in-place on d_out. 1 block per row.
// ---------------------------------------------------------------------------
__global__ __launch_bounds__(256) void ln_kernel(
    const float* __restrict__ x, const float* __restrict__ gamma,
    const float* __restrict__ beta, float* __restrict__ out) {
  __shared__ float red[8];
  const int row = blockIdx.x;
  const int t = threadIdx.x;
  float* orow = out + (size_t)row * DMODEL;
  const float* xrow = x + (size_t)row * DMODEL;

  const float4 o = *(const float4*)(orow + t * 4);
  const float4 xv = *(const float4*)(xrow + t * 4);
  float y0 = o.x + xv.x, y1 = o.y + xv.y, y2 = o.z + xv.z, y3 = o.w + xv.w;
  float s = y0 + y1 + y2 + y3;
  float sq = y0 * y0 + y1 * y1 + y2 * y2 + y3 * y3;
#pragma unroll
  for (int m = 1; m < 64; m <<= 1) {
    s += __shfl_xor(s, m);
    sq += __shfl_xor(sq, m);
  }
  const int w = t >> 6;
  if ((t & 63) == 0) { red[w] = s; red[4 + w] = sq; }
  __syncthreads();
  const float S = red[0] + red[1] + red[2] + red[3];
  const float SQ = red[4] + red[5] + red[6] + red[7];
  const float mu = S * (1.f / DMODEL);
  const float var = SQ * (1.f / DMODEL) - mu * mu;
  const float rstd = rsqrtf(var + 1e-5f);
  const float4 gv = *(const float4*)(gamma + t * 4);
  const float4 bv = *(const float4*)(beta + t * 4);
  float4 res;
  res.x = (y0 - mu) * rstd * gv.x + bv.x;
  res.y = (y1 - mu) * rstd * gv.y + bv.y;
  res.z = (y2 - mu) * rstd * gv.z + bv.z;
  res.w = (y3 - mu) * rstd * gv.w + bv.w;
  *(float4*)(orow + t * 4) = res;
}

// ---------------------------------------------------------------------------
extern "C" void kernel_launch(void* const* d_in, const int* in_sizes, int n_in,
                              void* d_out, int out_size, void* d_ws, size_t ws_size,
                              hipStream_t stream) {
  const float* x     = (const float*)d_in[0];
  const float* Wq    = (const float*)d_in[1];
  const float* bq    = (const float*)d_in[2];
  const float* Wk    = (const float*)d_in[3];
  const float* bk    = (const float*)d_in[4];
  const float* Wv    = (const float*)d_in[5];
  const float* bv    = (const float*)d_in[6];
  const float* gamma = (const float*)d_in[7];
  const float* beta  = (const float*)d_in[8];
  float* out = (float*)d_out;

  const size_t per = (size_t)BH * SEQ * DHEAD;  // 8388608 elems
  bf16_t* Qw = (bf16_t*)d_ws;
  bf16_t* Kw = Qw + per;
  bf16_t* Vw = Kw + per;

  qkv_kernel<<<dim3(8, 64), 256, 0, stream>>>(x, Wq, bq, Wk, bk, Wv, bv, Qw, Kw, Vw);
  attn_kernel<<<dim3(1024), 256, 0, stream>>>(Qw, Kw, Vw, out);
  ln_kernel<<<dim3(8192), 256, 0, stream>>>(x, gamma, beta, out);
}

// Round 2
// 197.364 us; speedup vs baseline: 1.2564x; 1.2564x over previous
//
#include <hip/hip_runtime.h>
#include <hip/hip_bf16.h>

typedef __bf16 bf16_t;
typedef bf16_t bf16x8 __attribute__((ext_vector_type(8)));
typedef bf16_t bf16x4 __attribute__((ext_vector_type(4)));
typedef float f32x4 __attribute__((ext_vector_type(4)));

#define SEQ    2048
#define DHEAD  64
#define DMODEL 1024
#define KVB    64
#define BHN    64   // B*H

__device__ __forceinline__ f32x4 mfma16(bf16x8 a, bf16x8 b, f32x4 c) {
  return __builtin_amdgcn_mfma_f32_16x16x32_bf16(a, b, c, 0, 0, 0);
}

// async global->LDS, 16B per lane. dest must be wave-uniform base (HW adds lane*16).
__device__ __forceinline__ void gload16(void* l, const void* g) {
  __builtin_amdgcn_global_load_lds(
      (const __attribute__((address_space(1))) unsigned int*)g,
      (__attribute__((address_space(3))) unsigned int*)l,
      16, 0, 0);
}

// ---------------------------------------------------------------------------
// Kernel 1: per-head QKV projection. x [B,S,D] fp32 ->
//   Qw [bh][s][64] bf16 (pre-scaled by 1/8), Kw [bh][s][64], VTw [bh][64][s].
// grid (8, 64), 256 thr. W staged in LDS as bf16 (swizzled), frags via b128.
// ---------------------------------------------------------------------------
__global__ __launch_bounds__(256) void qkv_kernel(
    const float* __restrict__ x,
    const float* __restrict__ Wq, const float* __restrict__ bq,
    const float* __restrict__ Wk, const float* __restrict__ bk,
    const float* __restrict__ Wv, const float* __restrict__ bv,
    bf16_t* __restrict__ Qw, bf16_t* __restrict__ Kw, bf16_t* __restrict__ VTw) {
  __shared__ __align__(16) char x_lds[256 * 128];  // 256 rows x 64 bf16, swizzled
  __shared__ __align__(16) char w_lds[8192];       // WT[e][d] bf16 swizzled; reused for V-transpose

  const int bh = blockIdx.y;
  const int b = bh >> 4, h = bh & 15;
  const int s0 = blockIdx.x * 256;
  const int t = threadIdx.x;
  const int w = t >> 6, lane = t & 63;
  const int lo = lane & 15, g = lane >> 4;

  // stage x head-slice into LDS as bf16, XOR-swizzled 128B rows
#pragma unroll
  for (int p = 0; p < 8; ++p) {
    const int row = p * 32 + (t >> 3);
    const int c = t & 7;
    const float* xp = x + ((size_t)(b * SEQ + s0 + row)) * DMODEL + h * DHEAD + c * 8;
    const float4 f0 = *(const float4*)xp;
    const float4 f1 = *(const float4*)(xp + 4);
    bf16x8 v;
    v[0] = (bf16_t)f0.x; v[1] = (bf16_t)f0.y; v[2] = (bf16_t)f0.z; v[3] = (bf16_t)f0.w;
    v[4] = (bf16_t)f1.x; v[5] = (bf16_t)f1.y; v[6] = (bf16_t)f1.z; v[7] = (bf16_t)f1.w;
    *(bf16x8*)(x_lds + row * 128 + ((c * 16) ^ ((row & 7) << 4))) = v;
  }
  __syncthreads();

  for (int wi = 0; wi < 3; ++wi) {
    const float* Wp = (wi == 0) ? Wq : (wi == 1) ? Wk : Wv;
    const float* Bp = (wi == 0) ? bq : (wi == 1) ? bk : bv;
    bf16_t* Op      = (wi == 0) ? Qw : Kw;   // wi==2 goes through the VT path

    if (wi > 0) __syncthreads();  // prior users of w_lds done
    // stage WT[e][d] bf16 swizzled (coalesced float4 reads of W[h][d][:])
    {
      const int d = t >> 2, e0 = (t & 3) * 16;
      const float* wp = Wp + (size_t)(h * 64 + d) * 64 + e0;
      const float4 f0 = *(const float4*)(wp);
      const float4 f1 = *(const float4*)(wp + 4);
      const float4 f2 = *(const float4*)(wp + 8);
      const float4 f3 = *(const float4*)(wp + 12);
      float vals[16];
      vals[0] = f0.x; vals[1] = f0.y; vals[2] = f0.z; vals[3] = f0.w;
      vals[4] = f1.x; vals[5] = f1.y; vals[6] = f1.z; vals[7] = f1.w;
      vals[8] = f2.x; vals[9] = f2.y; vals[10] = f2.z; vals[11] = f2.w;
      vals[12] = f3.x; vals[13] = f3.y; vals[14] = f3.z; vals[15] = f3.w;
#pragma unroll
      for (int j = 0; j < 16; ++j) {
        const int e = e0 + j;
        *(bf16_t*)(w_lds + e * 128 + ((2 * d) ^ ((e & 7) << 4))) = (bf16_t)vals[j];
      }
    }
    __syncthreads();

    // B-frags: lane (lo,g): n=e=ct*16+lo, k=d=ks*32+g*8+i
    bf16x8 wf[2][4];
    float bias[4];
#pragma unroll
    for (int ct = 0; ct < 4; ++ct) {
      bias[ct] = Bp[h * 64 + ct * 16 + lo];
#pragma unroll
      for (int ks = 0; ks < 2; ++ks)
        wf[ks][ct] = *(const bf16x8*)(w_lds + (ct * 16 + lo) * 128 +
                                      ((ks * 64 + g * 16) ^ ((lo & 7) << 4)));
    }
    if (wi == 2) __syncthreads();  // about to reuse w_lds as VT staging

    const float sc = (wi == 0) ? 0.125f : 1.0f;
#pragma unroll
    for (int it = 0; it < 4; ++it) {
      const int r0 = it * 64 + w * 16;
      bf16x8 xa[2];
#pragma unroll
      for (int ks = 0; ks < 2; ++ks) {
        const int row = r0 + lo;
        xa[ks] = *(const bf16x8*)(x_lds + row * 128 +
                                  ((ks * 64 + g * 16) ^ ((row & 7) << 4)));
      }
      f32x4 acc[4];
#pragma unroll
      for (int ct = 0; ct < 4; ++ct) {
        f32x4 a = (f32x4){0.f, 0.f, 0.f, 0.f};
        a = mfma16(xa[0], wf[0][ct], a);
        a = mfma16(xa[1], wf[1][ct], a);
        acc[ct] = a;
      }
      if (wi < 2) {
#pragma unroll
        for (int ct = 0; ct < 4; ++ct)
#pragma unroll
          for (int r = 0; r < 4; ++r) {
            const int srow = s0 + r0 + g * 4 + r;
            Op[((size_t)bh * SEQ + srow) * DHEAD + ct * 16 + lo] =
                (bf16_t)((acc[ct][r] + bias[ct]) * sc);
          }
      } else {
        // V: transpose via LDS -> coalesced VT[bh][e][s] stores
#pragma unroll
        for (int ct = 0; ct < 4; ++ct) {
          bf16x4 pk;
#pragma unroll
          for (int r = 0; r < 4; ++r) pk[r] = (bf16_t)(acc[ct][r] + bias[ct]);
          *(bf16x4*)(w_lds + (ct * 16 + lo) * 128 +
                     ((w * 32 + g * 8) ^ ((lo & 7) << 4))) = pk;
        }
        __syncthreads();
        {
          const int e = t >> 2, c4 = t & 3;
          const int sw = (e & 7) << 4;
          const bf16x8 v0 = *(const bf16x8*)(w_lds + e * 128 + ((c4 * 32) ^ sw));
          const bf16x8 v1 = *(const bf16x8*)(w_lds + e * 128 + ((c4 * 32 + 16) ^ sw));
          bf16_t* vp = VTw + ((size_t)bh * DHEAD + e) * SEQ + s0 + it * 64 + c4 * 16;
          *(bf16x8*)(vp) = v0;
          *(bf16x8*)(vp + 8) = v1;
        }
        __syncthreads();
      }
    }
  }
}

// ---------------------------------------------------------------------------
// Kernel 2: causal flash attention. 512 blocks (2/CU), 4 waves, QBLK=128
// (32 q/wave), KVB=64. Double-buffered gload_lds staging (pre-swizzled src),
// bf16 P in LDS, defer-max. Pairs (p, 15-p) -> uniform 36 kv-steps/block.
// ---------------------------------------------------------------------------
__global__ __launch_bounds__(256) void attn_kernel(
    const bf16_t* __restrict__ Qw, const bf16_t* __restrict__ Kw,
    const bf16_t* __restrict__ VTw, float* __restrict__ Out) {
  __shared__ __align__(16) char stage_lds[2][16384];  // [buf]: K 8KB | VT 8KB
  __shared__ __align__(16) char p_lds[4][4096];       // per-wave P[32 q][64 kv] bf16 swizzled

  const int f = blockIdx.x;
  const int bh = (f & 7) * 8 + ((f >> 3) & 7);  // cluster 8 bh per XCD
  const int pair = f >> 6;                      // 0..7
  const int b = bh >> 4, h = bh & 15;

  const int t = threadIdx.x;
  const int w = t >> 6, lane = t & 63;
  const int lo = lane & 15, g = lane >> 4;
  char* pbase = &p_lds[w][0];

  // staging constants: dest linear row = p*32 + w*8 + (lane>>3); swizzled source col
  const int strow = w * 8 + (lane >> 3);
  const int scol = ((lane & 7) * 16) ^ ((lane >> 3) << 4);
  const char* Kbase = (const char*)(Kw + (size_t)bh * SEQ * DHEAD);
  const char* Vbase = (const char*)(VTw + (size_t)bh * DHEAD * SEQ);
  const bf16_t* Qb = Qw + (size_t)bh * SEQ * DHEAD;

  for (int half = 0; half < 2; ++half) {
    const int qt = half ? (15 - pair) : pair;
    const int q0 = qt * 128;
    const int kts = 2 * qt + 2;

    // Q B-frags: 2 subs x 16 q each; lane holds q=qs0+lo, d=ks*32+g*8..+7
    bf16x8 qf[2][2];
#pragma unroll
    for (int s = 0; s < 2; ++s) {
      const bf16_t* qp = Qb + (size_t)(q0 + w * 32 + s * 16 + lo) * DHEAD + g * 8;
      qf[s][0] = *(const bf16x8*)(qp);
      qf[s][1] = *(const bf16x8*)(qp + 32);
    }
    float m_run[2] = {-1e30f, -1e30f};
    float l_run[2] = {0.f, 0.f};
    f32x4 oacc[2][4];
#pragma unroll
    for (int s = 0; s < 2; ++s)
#pragma unroll
      for (int dt = 0; dt < 4; ++dt) oacc[s][dt] = (f32x4){0.f, 0.f, 0.f, 0.f};

    __syncthreads();  // all prior LDS reads done before restaging buf 0
    {
      char* db = &stage_lds[0][0];
#pragma unroll
      for (int p = 0; p < 2; ++p) {
        gload16(db + p * 4096 + w * 1024,
                Kbase + (size_t)(p * 32 + strow) * 128 + scol);
        gload16(db + 8192 + p * 4096 + w * 1024,
                Vbase + (size_t)(p * 32 + strow) * 4096 + scol);
      }
    }
    int cur = 0;
    for (int kt = 0; kt < kts; ++kt) {
      const int kv0 = kt * KVB;
      __syncthreads();  // implicit vmcnt(0): tile kt landed; prev reads of buf^1 done
      if (kt + 1 < kts) {
        const int nk = kv0 + KVB;
        char* db = &stage_lds[cur ^ 1][0];
#pragma unroll
        for (int p = 0; p < 2; ++p) {
          gload16(db + p * 4096 + w * 1024,
                  Kbase + (size_t)(nk + p * 32 + strow) * 128 + scol);
          gload16(db + 8192 + p * 4096 + w * 1024,
                  Vbase + (size_t)(p * 32 + strow) * 4096 + (size_t)nk * 2 + scol);
        }
      }
      const char* kb = &stage_lds[cur][0];
      const char* vb = kb + 8192;

      // K A-frags once, shared by both q-subs
      bf16x8 kf[2][4];
#pragma unroll
      for (int ks = 0; ks < 2; ++ks)
#pragma unroll
        for (int ct = 0; ct < 4; ++ct)
          kf[ks][ct] = *(const bf16x8*)(kb + (ct * 16 + lo) * 128 +
                                        ((ks * 64 + g * 16) ^ ((lo & 7) << 4)));
      // QK^T (swapped): S^T[kv][q], q=lo, kv=ct*16+g*4+r
      f32x4 sa[2][4];
#pragma unroll
      for (int s = 0; s < 2; ++s) {
        const int qs0 = q0 + w * 32 + s * 16;
        if (kv0 > qs0 + 15) continue;  // fully masked sub (wave-uniform)
#pragma unroll
        for (int ct = 0; ct < 4; ++ct) {
          f32x4 a = (f32x4){0.f, 0.f, 0.f, 0.f};
          a = mfma16(kf[0][ct], qf[s][0], a);
          a = mfma16(kf[1][ct], qf[s][1], a);
          sa[s][ct] = a;
        }
      }
      // softmax + P write (bf16, swizzled)
#pragma unroll
      for (int s = 0; s < 2; ++s) {
        const int qs0 = q0 + w * 32 + s * 16;
        if (kv0 > qs0 + 15) continue;
        const int q = qs0 + lo;
        if (kv0 + 63 > qs0) {
#pragma unroll
          for (int ct = 0; ct < 4; ++ct)
#pragma unroll
            for (int r = 0; r < 4; ++r) {
              const int kv = kv0 + ct * 16 + g * 4 + r;
              if (kv > q) sa[s][ct][r] = -1e30f;
            }
        }
        float mt = -1e30f;
#pragma unroll
        for (int ct = 0; ct < 4; ++ct)
          mt = fmaxf(mt, fmaxf(fmaxf(sa[s][ct][0], sa[s][ct][1]),
                               fmaxf(sa[s][ct][2], sa[s][ct][3])));
        mt = fmaxf(mt, __shfl_xor(mt, 16));
        mt = fmaxf(mt, __shfl_xor(mt, 32));
        if (__any(mt > m_run[s] + 8.f)) {  // defer-max: rescale only when needed
          const float mn = fmaxf(m_run[s], mt);
          const float rs = __expf(m_run[s] - mn);
          l_run[s] *= rs;
          m_run[s] = mn;
#pragma unroll
          for (int r = 0; r < 4; ++r) {
            const float fr = __shfl(rs, g * 4 + r);
#pragma unroll
            for (int dt = 0; dt < 4; ++dt) oacc[s][dt][r] *= fr;
          }
        }
        float lt = 0.f;
        const float m = m_run[s];
#pragma unroll
        for (int ct = 0; ct < 4; ++ct) {
          bf16x4 pk;
#pragma unroll
          for (int r = 0; r < 4; ++r) {
            const float pv = __expf(sa[s][ct][r] - m);
            lt += pv;
            pk[r] = (bf16_t)pv;
          }
          *(bf16x4*)(pbase + (s * 16 + lo) * 128 +
                     ((ct * 32 + g * 8) ^ ((lo & 7) << 4))) = pk;
        }
        lt += __shfl_xor(lt, 16);
        lt += __shfl_xor(lt, 32);
        l_run[s] += lt;
      }
      // V B-frags once, shared by both q-subs
      bf16x8 vf[2][4];
#pragma unroll
      for (int ks = 0; ks < 2; ++ks)
#pragma unroll
        for (int dt = 0; dt < 4; ++dt)
          vf[ks][dt] = *(const bf16x8*)(vb + (dt * 16 + lo) * 128 +
                                        ((ks * 64 + g * 16) ^ ((lo & 7) << 4)));
      // PV
#pragma unroll
      for (int s = 0; s < 2; ++s) {
        const int qs0 = q0 + w * 32 + s * 16;
        if (kv0 > qs0 + 15) continue;
#pragma unroll
        for (int ks = 0; ks < 2; ++ks) {
          const bf16x8 pa = *(const bf16x8*)(pbase + (s * 16 + lo) * 128 +
                                             ((ks * 64 + g * 16) ^ ((lo & 7) << 4)));
#pragma unroll
          for (int dt = 0; dt < 4; ++dt)
            oacc[s][dt] = mfma16(pa, vf[ks][dt], oacc[s][dt]);
        }
      }
      cur ^= 1;
    }
    // epilogue: O/l -> d_out fp32
#pragma unroll
    for (int s = 0; s < 2; ++s) {
      const float inv = 1.f / l_run[s];
#pragma unroll
      for (int r = 0; r < 4; ++r) {
        const float fr = __shfl(inv, g * 4 + r);
        const int srow = q0 + w * 32 + s * 16 + g * 4 + r;
        float* op = Out + ((size_t)b * SEQ + srow) * DMODEL + h * DHEAD;
#pragma unroll
        for (int dt = 0; dt < 4; ++dt) op[dt * 16 + lo] = oacc[s][dt][r] * fr;
      }
    }
  }
}

// ---------------------------------------------------------------------------
// Kernel 3: residual add + LayerNorm, in-place on d_out. 1 block per row.
// ---------------------------------------------------------------------------
__global__ __launch_bounds__(256) void ln_kernel(
    const float* __restrict__ x, const float* __restrict__ gamma,
    const float* __restrict__ beta, float* __restrict__ out) {
  __shared__ float red[8];
  const int row = blockIdx.x;
  const int t = threadIdx.x;
  float* orow = out + (size_t)row * DMODEL;
  const float* xrow = x + (size_t)row * DMODEL;

  const float4 o = *(const float4*)(orow + t * 4);
  const float4 xv = *(const float4*)(xrow + t * 4);
  float y0 = o.x + xv.x, y1 = o.y + xv.y, y2 = o.z + xv.z, y3 = o.w + xv.w;
  float s = y0 + y1 + y2 + y3;
  float sq = y0 * y0 + y1 * y1 + y2 * y2 + y3 * y3;
#pragma unroll
  for (int m = 1; m < 64; m <<= 1) {
    s += __shfl_xor(s, m);
    sq += __shfl_xor(sq, m);
  }
  const int w = t >> 6;
  if ((t & 63) == 0) { red[w] = s; red[4 + w] = sq; }
  __syncthreads();
  const float S = red[0] + red[1] + red[2] + red[3];
  const float SQ = red[4] + red[5] + red[6] + red[7];
  const float mu = S * (1.f / DMODEL);
  const float var = SQ * (1.f / DMODEL) - mu * mu;
  const float rstd = rsqrtf(var + 1e-5f);
  const float4 gv = *(const float4*)(gamma + t * 4);
  const float4 bv = *(const float4*)(beta + t * 4);
  float4 res;
  res.x = (y0 - mu) * rstd * gv.x + bv.x;
  res.y = (y1 - mu) * rstd * gv.y + bv.y;
  res.z = (y2 - mu) * rstd * gv.z + bv.z;
  res.w = (y3 - mu) * rstd * gv.w + bv.w;
  *(float4*)(orow + t * 4) = res;
}

// ---------------------------------------------------------------------------
extern "C" void kernel_launch(void* const* d_in, const int* in_sizes, int n_in,
                              void* d_out, int out_size, void* d_ws, size_t ws_size,
                              hipStream_t stream) {
  const float* x     = (const float*)d_in[0];
  const float* Wq    = (const float*)d_in[1];
  const float* bq    = (const float*)d_in[2];
  const float* Wk    = (const float*)d_in[3];
  const float* bk    = (const float*)d_in[4];
  const float* Wv    = (const float*)d_in[5];
  const float* bv    = (const float*)d_in[6];
  const float* gamma = (const float*)d_in[7];
  const float* beta  = (const float*)d_in[8];
  float* out = (float*)d_out;

  const size_t per = (size_t)BHN * SEQ * DHEAD;  // 8388608 elems
  bf16_t* Qw  = (bf16_t*)d_ws;
  bf16_t* Kw  = Qw + per;
  bf16_t* VTw = Kw + per;

  qkv_kernel<<<dim3(8, 64), 256, 0, stream>>>(x, Wq, bq, Wk, bk, Wv, bv, Qw, Kw, VTw);
  attn_kernel<<<dim3(512), 256, 0, stream>>>(Qw, Kw, VTw, out);
  ln_kernel<<<dim3(8192), 256, 0, stream>>>(x, gamma, beta, out);
}